// Round 12
// baseline (153.653 us; speedup 1.0000x reference)
//
#include <hip/hip_runtime.h>
#include <hip/hip_bf16.h>
#include <stdint.h>

#define CCH 256
#define NPIX 4096      // 64*64
#define NH 8
#define M2 2560        // K*2*S
#define LOG2E 1.44269504088896f
#define GN_NB 32

typedef __attribute__((ext_vector_type(8))) short short8;
typedef __attribute__((ext_vector_type(4))) float f32x4;

__device__ __forceinline__ uint16_t f2bfu(float f) {
    uint32_t u = __builtin_bit_cast(uint32_t, f);
    return (uint16_t)((u + 0x7FFFu + ((u >> 16) & 1u)) >> 16);   // RNE
}
__device__ __forceinline__ uint32_t pack_bf2(float a, float b) {
    return (uint32_t)f2bfu(a) | ((uint32_t)f2bfu(b) << 16);
}
__device__ __forceinline__ short8 u4_to_s8(uint4 v) {
    return __builtin_bit_cast(short8, v);
}

// ---------------- prepack feature weights -> bf16 (B-frag-ready [co][ci]) ----------------
__global__ void prep_wb(const float* __restrict__ wq, const float* __restrict__ wsm,
                        uint16_t* __restrict__ WB) {
    int idx = blockIdx.x * 256 + threadIdx.x;     // 0..131071
    const float* src = (idx < 65536) ? wq : wsm;
    WB[idx] = f2bfu(src[idx & 65535]);
}

// ---------------- patch-weighted sums of x (linearity: centroids = W.psum/fgs + b) ----------
__global__ __launch_bounds__(256) void patch_sum(
        const float* __restrict__ x0, const float* __restrict__ x1,
        const float* __restrict__ x2, const float* __restrict__ x3,
        const float* __restrict__ dox, uint16_t* __restrict__ PS,
        float* __restrict__ inv, float* __restrict__ mbias) {
    int z = blockIdx.z;
    int sc = z / 5, k = z % 5;
    const float* xim = ((sc == 0) ? x0 : (sc == 1) ? x1 : (sc == 2) ? x2 : x3)
                       + (size_t)(k + 1) * CCH * NPIX;    // s-images 1..5
    int p1 = blockIdx.x, chq = blockIdx.y;
    int tid = threadIdx.x;
    int cloc = tid >> 6, col = tid & 63;
    __shared__ float wls[4][64];
    __shared__ uint16_t pst[2][16][72];
    wls[cloc][col] = dox[(size_t)k * 65536 + (size_t)(16 * p1 + 4 * cloc) * 256 + 4 * col];
    __syncthreads();
    float w0 = wls[0][col], w1 = wls[1][col], w2 = wls[2][col], w3 = wls[3][col];
    const float* xbase = xim + p1 * 256 + col;
#pragma unroll 4
    for (int it = 0; it < 16; ++it) {
        int c = chq * 64 + it * 4 + cloc;
        const float* xp = xbase + (size_t)c * NPIX;
        float v0 = xp[0], v1 = xp[64], v2 = xp[128], v3 = xp[192];
        float pf = w0 * v0 + w1 * v1 + w2 * v2 + w3 * v3;
        float pb = (v0 + v1 + v2 + v3) - pf;
        pf += __shfl_xor(pf, 1); pf += __shfl_xor(pf, 2);
        pb += __shfl_xor(pb, 1); pb += __shfl_xor(pb, 2);
        if ((col & 3) == 0) {
            int q = col >> 2, cl = it * 4 + cloc;
            pst[0][q][cl] = f2bfu(pf);
            pst[1][q][cl] = f2bfu(pb);
        }
    }
    if (chq == 0 && tid < 64) {
        float ws = w0 + w1 + w2 + w3;
        ws += __shfl_xor(ws, 1); ws += __shfl_xor(ws, 2);
        if ((col & 3) == 0) {
            int s = p1 * 16 + (col >> 2);
            float fsum = ws, bsum = 16.f - ws;
            int mf = k * 512 + s, mbk = mf + 256;
            mbias[sc * M2 + mf]  = (fsum < 1.f) ? -1e30f : 0.f;
            mbias[sc * M2 + mbk] = (bsum < 1.f) ? -1e30f : 0.f;
            inv[(size_t)(z * 2 + 0) * 256 + s] = 1.f / fmaxf(fsum, 1e-6f);
            inv[(size_t)(z * 2 + 1) * 256 + s] = 1.f / fmaxf(bsum, 1e-6f);
        }
    }
    __syncthreads();
    int fb = tid >> 7, rem = tid & 127;
    int q = rem >> 3, chunk = rem & 7;
    uint4 v = *(const uint4*)&pst[fb][q][chunk * 8];
    int s = p1 * 16 + q;
    *(uint4*)&PS[((size_t)(z * 2 + fb) * 256 + s) * CCH + chq * 64 + chunk * 8] = v;
}

// ---------------- centroid GEMM: Cs = W.(psum)*inv + b ----------------
__global__ __launch_bounds__(256) void cent_gemm(
        const uint16_t* __restrict__ PS, const uint16_t* __restrict__ WB,
        const float* __restrict__ bs, const float* __restrict__ inv,
        uint16_t* __restrict__ Csbf) {
    int tid = threadIdx.x, lane = tid & 63, wid = tid >> 6;
    int lp = lane & 15, g = lane >> 4;
    int rowb = blockIdx.x * 128 + wid * 32;
    int cob = blockIdx.y * 64;
    const uint16_t* wsb = WB + 65536;
    f32x4 acc[2][4] = {};
#pragma unroll
    for (int ks = 0; ks < 8; ++ks) {
        int k0 = ks * 32;
        uint4 a0 = *(const uint4*)(PS + (size_t)(rowb + lp) * CCH + k0 + g * 8);
        uint4 a1 = *(const uint4*)(PS + (size_t)(rowb + 16 + lp) * CCH + k0 + g * 8);
        short8 af[2] = {u4_to_s8(a0), u4_to_s8(a1)};
        short8 b[4];
#pragma unroll
        for (int t = 0; t < 4; ++t) {
            uint4 bw = *(const uint4*)(wsb + (size_t)(cob + t * 16 + lp) * 256 + k0 + g * 8);
            b[t] = u4_to_s8(bw);
        }
#pragma unroll
        for (int m = 0; m < 2; ++m)
#pragma unroll
            for (int t = 0; t < 4; ++t)
                acc[m][t] = __builtin_amdgcn_mfma_f32_16x16x32_bf16(af[m], b[t], acc[m][t], 0, 0, 0);
    }
#pragma unroll
    for (int m = 0; m < 2; ++m)
#pragma unroll
        for (int t = 0; t < 4; ++t) {
            int co = cob + t * 16 + lp;
            int h = co >> 5, d = co & 31;
            float bv = bs[co];
#pragma unroll
            for (int r = 0; r < 4; ++r) {
                int row = rowb + m * 16 + g * 4 + r;
                int zz = row >> 9, fb = (row >> 8) & 1, s = row & 255;
                int scc = zz / 5, kk = zz % 5;
                int slot = kk * 512 + fb * 256 + s;
                float val = acc[m][t][r] * inv[row] + bv;
                Csbf[(((size_t)scc * NH + h) * M2 + slot) * 32 + d] = f2bfu(val);
            }
        }
}

// ---------------- Q GEMM (img 0 only) ----------------
__global__ __launch_bounds__(512) void q_gemm(
        const float* __restrict__ x0, const float* __restrict__ x1,
        const float* __restrict__ x2, const float* __restrict__ x3,
        const uint16_t* __restrict__ WB, const float* __restrict__ bq,
        uint16_t* __restrict__ Qbf) {
    int sc = blockIdx.y;
    const float* xim = (sc == 0) ? x0 : (sc == 1) ? x1 : (sc == 2) ? x2 : x3;  // img 0
    int p0 = blockIdx.x * 64;
    int tid = threadIdx.x, lane = tid & 63, wid = tid >> 6;
    int lp = lane & 15, g = lane >> 4;
    int wm = wid >> 1, wn = wid & 1;
    __shared__ uint32_t Al[16][68];
    f32x4 acc[8] = {};
#pragma unroll
    for (int ks = 0; ks < 8; ++ks) {
        int k0 = ks * 32;
        __syncthreads();
        if (tid < 256) {
            int rp = tid >> 4, f4i = tid & 15;
            float4 v0 = *(const float4*)(xim + (size_t)(k0 + 2 * rp) * NPIX + p0 + f4i * 4);
            float4 v1 = *(const float4*)(xim + (size_t)(k0 + 2 * rp + 1) * NPIX + p0 + f4i * 4);
            *(uint4*)&Al[rp][f4i * 4] = make_uint4(
                pack_bf2(v0.x, v1.x), pack_bf2(v0.y, v1.y),
                pack_bf2(v0.z, v1.z), pack_bf2(v0.w, v1.w));
        }
        __syncthreads();
        short8 b[8];
#pragma unroll
        for (int tn = 0; tn < 8; ++tn) {
            uint4 bw = *(const uint4*)(WB + (size_t)(wn * 128 + tn * 16 + lp) * 256 + k0 + g * 8);
            b[tn] = u4_to_s8(bw);
        }
        int px = wm * 16 + lp;
        uint4 av = make_uint4(Al[4 * g + 0][px], Al[4 * g + 1][px],
                              Al[4 * g + 2][px], Al[4 * g + 3][px]);
        short8 af = u4_to_s8(av);
#pragma unroll
        for (int tn = 0; tn < 8; ++tn)
            acc[tn] = __builtin_amdgcn_mfma_f32_16x16x32_bf16(af, b[tn], acc[tn], 0, 0, 0);
    }
#pragma unroll
    for (int tn = 0; tn < 8; ++tn) {
        int co = wn * 128 + tn * 16 + lp;
        float bv = bq[co];
#pragma unroll
        for (int r = 0; r < 4; ++r) {
            int row = p0 + wm * 16 + g * 4 + r;
            Qbf[((size_t)(sc * NPIX + row)) * CCH + co] = f2bfu((acc[tn][r] + bv) * LOG2E);
        }
    }
}

// ---------------- attention v5: v4 + next-chunk register prefetch (issue-early) ----------
// grid (16 px-tiles of 256, 8 heads, 16 = sc*4+split). 4 waves x 64px (4 Q-frags each).
__global__ __launch_bounds__(256) void attn_v5(
        const uint16_t* __restrict__ Qbf, const uint16_t* __restrict__ Csbf,
        const float* __restrict__ mbias, float* __restrict__ sfbuf) {
    int head = blockIdx.y;
    int sc = blockIdx.z >> 2, split = blockIdx.z & 3;
    int tid = threadIdx.x;
    int lane = tid & 63, wid = tid >> 6;
    int lp = lane & 15, g = lane >> 4;
    int p0w = blockIdx.x * 256 + wid * 64;

    const uint16_t* Qs = Qbf + (size_t)sc * NPIX * CCH;
    const uint16_t* csb = Csbf + ((size_t)sc * NH + head) * M2 * 32;
    const float* mb = mbias + sc * M2;

    short8 aq[4];
#pragma unroll
    for (int m = 0; m < 4; m++) {
        uint4 qv = *(const uint4*)(Qs + (size_t)(p0w + m * 16 + lp) * CCH + head * 32 + g * 8);
        aq[m] = u4_to_s8(qv);
    }

    float sfg[4][4] = {}, sbg[4][4] = {};
    int cbeg = split * 640;
    // prologue: load chunk 0 fragments
    short8 bf[4];
    float mbv[4];
#pragma unroll
    for (int t = 0; t < 4; t++) {
        int row = cbeg + t * 16 + lp;
        bf[t] = u4_to_s8(*(const uint4*)(csb + (size_t)row * 32 + g * 8));
        mbv[t] = mb[row];
    }
#pragma unroll 2
    for (int c0loc = 0; c0loc < 640; c0loc += 64) {
        int c0 = cbeg + c0loc;
        bool fg = ((c0 & 511) < 256);   // uniform per 64-chunk
        // issue next chunk's loads BEFORE the compute phase (latency hides under MFMA+exp)
        short8 nbf[4];
        float nmbv[4];
        if (c0loc < 576) {
#pragma unroll
            for (int t = 0; t < 4; t++) {
                int row = c0 + 64 + t * 16 + lp;
                nbf[t] = u4_to_s8(*(const uint4*)(csb + (size_t)row * 32 + g * 8));
                nmbv[t] = mb[row];
            }
        }
        if (fg) {
#pragma unroll
            for (int m = 0; m < 4; m++)
#pragma unroll
                for (int t = 0; t < 4; t++) {
                    f32x4 c = {mbv[t], mbv[t], mbv[t], mbv[t]};
                    c = __builtin_amdgcn_mfma_f32_16x16x32_bf16(aq[m], bf[t], c, 0, 0, 0);
#pragma unroll
                    for (int r = 0; r < 4; r++)
                        sfg[m][r] += __builtin_amdgcn_exp2f(c[r]);
                }
        } else {
#pragma unroll
            for (int m = 0; m < 4; m++)
#pragma unroll
                for (int t = 0; t < 4; t++) {
                    f32x4 c = {mbv[t], mbv[t], mbv[t], mbv[t]};
                    c = __builtin_amdgcn_mfma_f32_16x16x32_bf16(aq[m], bf[t], c, 0, 0, 0);
#pragma unroll
                    for (int r = 0; r < 4; r++)
                        sbg[m][r] += __builtin_amdgcn_exp2f(c[r]);
                }
        }
        if (c0loc < 576) {
#pragma unroll
            for (int t = 0; t < 4; t++) { bf[t] = nbf[t]; mbv[t] = nmbv[t]; }
        }
    }
#pragma unroll
    for (int m = 0; m < 4; m++)
#pragma unroll
        for (int r = 0; r < 4; r++) {
#pragma unroll
            for (int msk = 1; msk < 16; msk <<= 1) {
                sfg[m][r] += __shfl_xor(sfg[m][r], msk);
                sbg[m][r] += __shfl_xor(sbg[m][r], msk);
            }
        }
    if (lp == 0) {
        float* sf = sfbuf + (size_t)((sc * 4 + split) * 2) * NH * NPIX;
        float* so = sf + (size_t)head * NPIX;
        float* fo = sf + (size_t)(NH + head) * NPIX;
#pragma unroll
        for (int m = 0; m < 4; m++)
#pragma unroll
            for (int r = 0; r < 4; r++) {
                int px = p0w + m * 16 + g * 4 + r;
                so[px] = sfg[m][r] + sbg[m][r];
                fo[px] = sfg[m][r];
            }
    }
}

// ---------------- head mean over 4 split partials ----------------
__global__ void mean_heads3(const float* __restrict__ sfbuf, float* __restrict__ cm) {
    int idx = blockIdx.x * 256 + threadIdx.x;   // 16384
    int sc = idx >> 12, p = idx & 4095;
    const float* b = sfbuf + (size_t)sc * 4 * 2 * NH * NPIX;
    float acc = 0.f;
#pragma unroll
    for (int h = 0; h < NH; h++) {
        float sv = 0.f, fv = 0.f;
#pragma unroll
        for (int sp = 0; sp < 4; sp++) {
            sv += b[((size_t)(sp * 2) * NH + h) * NPIX + p];
            fv += b[((size_t)(sp * 2 + 1) * NH + h) * NPIX + p];
        }
        acc += fv / sv;
    }
    cm[idx] = 0.125f * acc;
}

// ---------------- conv weight prepack: Wk[ck][oc][32] bf16, zero-filled past K ----------------
__global__ void prep_w(const float* __restrict__ w, uint16_t* __restrict__ Wk,
                       int Cin, int Cout, int K2, int CK) {
    int idx = blockIdx.x * 256 + threadIdx.x;
    int total = CK * Cout * 32;
    if (idx >= total) return;
    int kk = idx & 31;
    int oc = (idx >> 5) % Cout;
    int ck = idx / (32 * Cout);
    int k = ck * 32 + kk;
    int tap = k / Cin, ic = k % Cin;
    float v = (tap < K2) ? w[((size_t)oc * Cin + ic) * K2 + tap] : 0.0f;
    Wk[idx] = f2bfu(v);
}

// ---------------- implicit-GEMM conv via MFMA ----------------
template<int CIN, int COUT, int KSZ>
__global__ __launch_bounds__(256) void conv_mfma(
        const float* __restrict__ in, const uint16_t* __restrict__ Wk,
        const float* __restrict__ bias, float* __restrict__ out) {
    constexpr int PAD = KSZ / 2;
    constexpr int NTAP = KSZ * KSZ;
    constexpr int K = CIN * NTAP;
    constexpr int CK = (K + 31) / 32;
    constexpr int PXP = 64 + 2 * PAD;
    constexpr int ICB = (CIN >= 8) ? CIN / 8 : 1;
    __shared__ uint16_t Xs[KSZ * PXP * CIN];
    int tid = threadIdx.x;
    int lane = tid & 63, wv = tid >> 6;
    int lp = lane & 15, g = lane >> 4;
    int y = blockIdx.x;
    int oc0 = blockIdx.y * 64;

    if (CIN >= 8) {
        for (int idx = tid; idx < KSZ * ICB * PXP; idx += 256) {
            int pxp = idx % PXP; int rem = idx / PXP;
            int icb = rem % ICB; int r = rem / ICB;
            int gy = y + r - PAD, gx = pxp - PAD;
            bool ok = ((unsigned)gy < 64u) && ((unsigned)gx < 64u);
            const float* ip = in + (size_t)(icb * 8) * NPIX + gy * 64 + gx;
            uint32_t wb[4];
#pragma unroll
            for (int j = 0; j < 4; j++) {
                float v0 = ok ? ip[(size_t)(2 * j) * NPIX] : 0.f;
                float v1 = ok ? ip[(size_t)(2 * j + 1) * NPIX] : 0.f;
                wb[j] = pack_bf2(v0, v1);
            }
            *(uint4*)&Xs[(size_t)idx * 8] = make_uint4(wb[0], wb[1], wb[2], wb[3]);
        }
    } else {
        for (int idx = tid; idx < KSZ * PXP; idx += 256) {
            int pxp = idx % PXP; int r = idx / PXP;
            int gy = y + r - PAD, gx = pxp - PAD;
            bool ok = ((unsigned)gy < 64u) && ((unsigned)gx < 64u);
            const float* ip = in + (size_t)gy * 64 + gx;
            float v0 = ok ? ip[0] : 0.f, v1 = ok ? ip[NPIX] : 0.f;
            float v2 = ok ? ip[2 * NPIX] : 0.f, v3 = ok ? ip[3 * NPIX] : 0.f;
            *(uint2*)&Xs[(size_t)idx * 4] = make_uint2(pack_bf2(v0, v1), pack_bf2(v2, v3));
        }
    }
    __syncthreads();

    int tmb, tme, tn;
    if (COUT >= 64) { tn = wv; tmb = 0; tme = 4; }
    else            { tn = 0;  tmb = wv; tme = wv + 1; }
    int oc = oc0 + tn * 16 + lp;
    f32x4 acc[4] = {};

#pragma unroll
    for (int ck = 0; ck < CK; ck++) {
        const uint16_t* wp = Wk + ((size_t)ck * COUT + oc) * 32 + g * 8;
        uint4 bw = *(const uint4*)wp;
        short8 bfr = u4_to_s8(bw);
        if (CIN >= 8) {
            int gk = ck * 4 + g;
            int tap = gk / ICB; if (tap > NTAP - 1) tap = NTAP - 1;
            int icb = gk % ICB;
            int r = tap / KSZ, dx = tap % KSZ;
            int base = (r * ICB + icb) * PXP * 8;
            for (int tm = tmb; tm < tme; tm++) {
                int pxp = tm * 16 + lp + dx;
                uint4 av = *(const uint4*)&Xs[base + pxp * 8];
                short8 afr = u4_to_s8(av);
                acc[tm] = __builtin_amdgcn_mfma_f32_16x16x32_bf16(afr, bfr, acc[tm], 0, 0, 0);
            }
        } else {
            int gk = ck * 4 + g;
            int t0 = 2 * gk;     if (t0 > NTAP - 1) t0 = NTAP - 1;
            int t1 = 2 * gk + 1; if (t1 > NTAP - 1) t1 = NTAP - 1;
            int r0 = t0 / KSZ, dx0 = t0 % KSZ;
            int r1 = t1 / KSZ, dx1 = t1 % KSZ;
            for (int tm = tmb; tm < tme; tm++) {
                uint2 a0 = *(const uint2*)&Xs[((size_t)(r0 * PXP + tm * 16 + lp + dx0)) * 4];
                uint2 a1 = *(const uint2*)&Xs[((size_t)(r1 * PXP + tm * 16 + lp + dx1)) * 4];
                uint4 av = make_uint4(a0.x, a0.y, a1.x, a1.y);
                short8 afr = u4_to_s8(av);
                acc[tm] = __builtin_amdgcn_mfma_f32_16x16x32_bf16(afr, bfr, acc[tm], 0, 0, 0);
            }
        }
    }
    float bv = bias[oc];
    for (int tm = tmb; tm < tme; tm++)
#pragma unroll
        for (int r = 0; r < 4; r++) {
            int px = tm * 16 + g * 4 + r;
            out[(size_t)oc * NPIX + y * 64 + px] = acc[tm][r] + bv;
        }
}

// ---------------- group norm: stage 1 partial sums ----------------
__global__ __launch_bounds__(256) void gn_part(const float* __restrict__ in, int Cg,
                                               float* __restrict__ part) {
    int g = blockIdx.x, b = blockIdx.y;
    int n4 = Cg * 1024;
    const float4* base = (const float4*)(in + (size_t)g * Cg * NPIX);
    float s = 0.0f, s2 = 0.0f;
    for (int i = b * 256 + threadIdx.x; i < n4; i += GN_NB * 256) {
        float4 v = base[i];
        s += v.x + v.y + v.z + v.w;
        s2 = fmaf(v.x, v.x, s2); s2 = fmaf(v.y, v.y, s2);
        s2 = fmaf(v.z, v.z, s2); s2 = fmaf(v.w, v.w, s2);
    }
#pragma unroll
    for (int off = 32; off; off >>= 1) {
        s += __shfl_down(s, off);
        s2 += __shfl_down(s2, off);
    }
    __shared__ float rs[4], rs2[4];
    int w = threadIdx.x >> 6;
    if ((threadIdx.x & 63) == 0) { rs[w] = s; rs2[w] = s2; }
    __syncthreads();
    if (threadIdx.x == 0) {
        part[(g * GN_NB + b) * 2]     = rs[0] + rs[1] + rs[2] + rs[3];
        part[(g * GN_NB + b) * 2 + 1] = rs2[0] + rs2[1] + rs2[2] + rs2[3];
    }
}

// ---------------- group norm: stage 2 apply + relu ----------------
__global__ __launch_bounds__(256) void gn_apply_relu(const float* __restrict__ in, const float* __restrict__ part,
                                                     const float* __restrict__ gamma, const float* __restrict__ beta,
                                                     int Cg, float* __restrict__ out) {
    int idx4 = blockIdx.x * 256 + threadIdx.x;
    int c = idx4 >> 10;
    int g = c / Cg;
    float s = 0.0f, s2 = 0.0f;
#pragma unroll
    for (int b = 0; b < GN_NB; b++) {
        s  += part[(g * GN_NB + b) * 2];
        s2 += part[(g * GN_NB + b) * 2 + 1];
    }
    float n = (float)(Cg * NPIX);
    float mu = s / n;
    float rstd = rsqrtf(s2 / n - mu * mu + 1e-5f);
    float ga = gamma[c] * rstd;
    float be = beta[c] - mu * ga;
    float4 v = ((const float4*)in)[idx4];
    float4 o;
    o.x = fmaf(v.x, ga, be); o.x = o.x > 0.f ? o.x : 0.f;
    o.y = fmaf(v.y, ga, be); o.y = o.y > 0.f ? o.y : 0.f;
    o.z = fmaf(v.z, ga, be); o.z = o.z > 0.f ? o.z : 0.f;
    o.w = fmaf(v.w, ga, be); o.w = o.w > 0.f ? o.w : 0.f;
    ((float4*)out)[idx4] = o;
}

// ---------------- launch ----------------
extern "C" void kernel_launch(void* const* d_in, const int* in_sizes, int n_in,
                              void* d_out, int out_size, void* d_ws, size_t ws_size,
                              hipStream_t stream) {
    const float* x0 = (const float*)d_in[0];
    const float* x1 = (const float*)d_in[1];
    const float* x2 = (const float*)d_in[2];
    const float* x3 = (const float*)d_in[3];
    const float* dox = (const float*)d_in[4];
    const float* wq  = (const float*)d_in[5];
    const float* bq  = (const float*)d_in[6];
    const float* wsm = (const float*)d_in[7];
    const float* bs  = (const float*)d_in[8];
    const float* cw1 = (const float*)d_in[9];
    const float* cb1 = (const float*)d_in[10];
    const float* g1  = (const float*)d_in[11];
    const float* be1 = (const float*)d_in[12];
    const float* cw2 = (const float*)d_in[13];
    const float* cb2 = (const float*)d_in[14];
    const float* g2  = (const float*)d_in[15];
    const float* be2 = (const float*)d_in[16];
    const float* cw3 = (const float*)d_in[17];
    const float* cb3 = (const float*)d_in[18];
    const float* g3  = (const float*)d_in[19];
    const float* be3 = (const float*)d_in[20];

    // u16 region
    uint16_t* Qbf  = (uint16_t*)d_ws;                        // 4194304
    uint16_t* Csbf = Qbf + (size_t)4194304;                  // 2621440
    uint16_t* PS   = Csbf + (size_t)2621440;                 // 2621440
    uint16_t* WB   = PS + (size_t)2621440;                   // 131072
    uint16_t* Wk1  = WB + 131072;                            // 2048
    uint16_t* Wk2  = Wk1 + 2048;                             // 26624
    uint16_t* Wk3  = Wk2 + 26624;                            // 73728
    // float region
    float* fbase  = (float*)(Wk3 + 73728);
    float* mbias  = fbase;                 // 10240
    float* inv    = mbias + 10240;         // 10240
    float* sfbuf  = inv + 10240;           // 1048576
    float* cm     = sfbuf + 1048576;       // 16384
    float* h1     = cm + 16384;            // 65536
    float* h2     = h1 + 65536;            // 262144
    float* h3     = h2 + 262144;           // 524288
    float* gnpart = h3 + 524288;           // 256

    // prepacks (independent)
    prep_wb<<<512, 256, 0, stream>>>(wq, wsm, WB);
    prep_w<<<(4 * 16 * 32 + 255) / 256, 256, 0, stream>>>(cw1, Wk1, 4, 16, 25, 4);
    prep_w<<<(13 * 64 * 32 + 255) / 256, 256, 0, stream>>>(cw2, Wk2, 16, 64, 25, 13);
    prep_w<<<(18 * 128 * 32 + 255) / 256, 256, 0, stream>>>(cw3, Wk3, 64, 128, 9, 18);

    // pipeline
    patch_sum<<<dim3(16, 4, 20), 256, 0, stream>>>(x0, x1, x2, x3, dox, PS, inv, mbias);
    q_gemm<<<dim3(64, 4), 512, 0, stream>>>(x0, x1, x2, x3, WB, bq, Qbf);
    cent_gemm<<<dim3(80, 4), 256, 0, stream>>>(PS, WB, bs, inv, Csbf);
    attn_v5<<<dim3(16, NH, 16), 256, 0, stream>>>(Qbf, Csbf, mbias, sfbuf);
    mean_heads3<<<64, 256, 0, stream>>>(sfbuf, cm);

    conv_mfma<4, 16, 5><<<dim3(64, 1), 256, 0, stream>>>(cm, Wk1, cb1, h1);
    gn_part<<<dim3(4, GN_NB), 256, 0, stream>>>(h1, 4, gnpart);
    gn_apply_relu<<<(16 * 1024) / 256, 256, 0, stream>>>(h1, gnpart, g1, be1, 4, h1);

    conv_mfma<16, 64, 5><<<dim3(64, 1), 256, 0, stream>>>(h1, Wk2, cb2, h2);
    gn_part<<<dim3(4, GN_NB), 256, 0, stream>>>(h2, 16, gnpart);
    gn_apply_relu<<<(64 * 1024) / 256, 256, 0, stream>>>(h2, gnpart, g2, be2, 16, h2);

    conv_mfma<64, 128, 3><<<dim3(64, 2), 256, 0, stream>>>(h2, Wk3, cb3, h3);
    gn_part<<<dim3(4, GN_NB), 256, 0, stream>>>(h3, 32, gnpart);
    gn_apply_relu<<<(128 * 1024) / 256, 256, 0, stream>>>(h3, gnpart, g3, be3, 32, (float*)d_out);
}

// Round 13
// 147.248 us; speedup vs baseline: 1.0435x; 1.0435x over previous
//
#include <hip/hip_runtime.h>
#include <hip/hip_bf16.h>
#include <stdint.h>

#define CCH 256
#define NPIX 4096      // 64*64
#define NH 8
#define M2 2560        // K*2*S
#define LOG2E 1.44269504088896f
#define GN_NB 32

typedef __attribute__((ext_vector_type(8))) short short8;
typedef __attribute__((ext_vector_type(4))) float f32x4;

__device__ __forceinline__ uint16_t f2bfu(float f) {
    uint32_t u = __builtin_bit_cast(uint32_t, f);
    return (uint16_t)((u + 0x7FFFu + ((u >> 16) & 1u)) >> 16);   // RNE
}
__device__ __forceinline__ uint32_t pack_bf2(float a, float b) {
    return (uint32_t)f2bfu(a) | ((uint32_t)f2bfu(b) << 16);
}
__device__ __forceinline__ short8 u4_to_s8(uint4 v) {
    return __builtin_bit_cast(short8, v);
}

// ---------------- fused prepack: WB (feature weights) + conv Wk1/Wk2/Wk3 ----------------
__device__ __forceinline__ void prep_w_one(const float* __restrict__ w, uint16_t* __restrict__ Wk,
                                           int idx, int Cin, int Cout, int K2) {
    int kk = idx & 31;
    int oc = (idx >> 5) % Cout;
    int ck = idx / (32 * Cout);
    int k = ck * 32 + kk;
    int tap = k / Cin, ic = k % Cin;
    float v = (tap < K2) ? w[((size_t)oc * Cin + ic) * K2 + tap] : 0.0f;
    Wk[idx] = f2bfu(v);
}

__global__ void prep_all(const float* __restrict__ wq, const float* __restrict__ wsm,
                         const float* __restrict__ cw1, const float* __restrict__ cw2,
                         const float* __restrict__ cw3,
                         uint16_t* __restrict__ WB, uint16_t* __restrict__ Wk1,
                         uint16_t* __restrict__ Wk2, uint16_t* __restrict__ Wk3) {
    int idx = blockIdx.x * 256 + threadIdx.x;
    if (idx < 131072) {                       // WB: wq|wsm -> bf16
        const float* src = (idx < 65536) ? wq : wsm;
        WB[idx] = f2bfu(src[idx & 65535]);
        return;
    }
    idx -= 131072;
    if (idx < 2048)  { prep_w_one(cw1, Wk1, idx, 4, 16, 25);  return; }
    idx -= 2048;
    if (idx < 26624) { prep_w_one(cw2, Wk2, idx, 16, 64, 25); return; }
    idx -= 26624;
    if (idx < 73728) { prep_w_one(cw3, Wk3, idx, 64, 128, 9); return; }
}

// ---------------- patch-weighted sums of x (linearity: centroids = W.psum/fgs + b) ----------
__global__ __launch_bounds__(256) void patch_sum(
        const float* __restrict__ x0, const float* __restrict__ x1,
        const float* __restrict__ x2, const float* __restrict__ x3,
        const float* __restrict__ dox, uint16_t* __restrict__ PS,
        float* __restrict__ inv, float* __restrict__ mexpb) {
    int z = blockIdx.z;
    int sc = z / 5, k = z % 5;
    const float* xim = ((sc == 0) ? x0 : (sc == 1) ? x1 : (sc == 2) ? x2 : x3)
                       + (size_t)(k + 1) * CCH * NPIX;    // s-images 1..5
    int p1 = blockIdx.x, chq = blockIdx.y;
    int tid = threadIdx.x;
    int cloc = tid >> 6, col = tid & 63;
    __shared__ float wls[4][64];
    __shared__ uint16_t pst[2][16][72];
    wls[cloc][col] = dox[(size_t)k * 65536 + (size_t)(16 * p1 + 4 * cloc) * 256 + 4 * col];
    __syncthreads();
    float w0 = wls[0][col], w1 = wls[1][col], w2 = wls[2][col], w3 = wls[3][col];
    const float* xbase = xim + p1 * 256 + col;
#pragma unroll 4
    for (int it = 0; it < 16; ++it) {
        int c = chq * 64 + it * 4 + cloc;
        const float* xp = xbase + (size_t)c * NPIX;
        float v0 = xp[0], v1 = xp[64], v2 = xp[128], v3 = xp[192];
        float pf = w0 * v0 + w1 * v1 + w2 * v2 + w3 * v3;
        float pb = (v0 + v1 + v2 + v3) - pf;
        pf += __shfl_xor(pf, 1); pf += __shfl_xor(pf, 2);
        pb += __shfl_xor(pb, 1); pb += __shfl_xor(pb, 2);
        if ((col & 3) == 0) {
            int q = col >> 2, cl = it * 4 + cloc;
            pst[0][q][cl] = f2bfu(pf);
            pst[1][q][cl] = f2bfu(pb);
        }
    }
    if (chq == 0 && tid < 64) {
        float ws = w0 + w1 + w2 + w3;
        ws += __shfl_xor(ws, 1); ws += __shfl_xor(ws, 2);
        if ((col & 3) == 0) {
            int s = p1 * 16 + (col >> 2);
            float fsum = ws, bsum = 16.f - ws;
            int mf = k * 512 + s, mbk = mf + 256;
            mexpb[sc * M2 + mf]  = (fsum < 1.f) ? 0.f : 1.f;   // multiplicative mask
            mexpb[sc * M2 + mbk] = (bsum < 1.f) ? 0.f : 1.f;
            inv[(size_t)(z * 2 + 0) * 256 + s] = 1.f / fmaxf(fsum, 1e-6f);
            inv[(size_t)(z * 2 + 1) * 256 + s] = 1.f / fmaxf(bsum, 1e-6f);
        }
    }
    __syncthreads();
    int fb = tid >> 7, rem = tid & 127;
    int q = rem >> 3, chunk = rem & 7;
    uint4 v = *(const uint4*)&pst[fb][q][chunk * 8];
    int s = p1 * 16 + q;
    *(uint4*)&PS[((size_t)(z * 2 + fb) * 256 + s) * CCH + chq * 64 + chunk * 8] = v;
}

// ---------------- centroid GEMM: Cs = W.(psum)*inv + b ----------------
__global__ __launch_bounds__(256) void cent_gemm(
        const uint16_t* __restrict__ PS, const uint16_t* __restrict__ WB,
        const float* __restrict__ bs, const float* __restrict__ inv,
        uint16_t* __restrict__ Csbf) {
    int tid = threadIdx.x, lane = tid & 63, wid = tid >> 6;
    int lp = lane & 15, g = lane >> 4;
    int rowb = blockIdx.x * 128 + wid * 32;
    int cob = blockIdx.y * 64;
    const uint16_t* wsb = WB + 65536;
    f32x4 acc[2][4] = {};
#pragma unroll
    for (int ks = 0; ks < 8; ++ks) {
        int k0 = ks * 32;
        uint4 a0 = *(const uint4*)(PS + (size_t)(rowb + lp) * CCH + k0 + g * 8);
        uint4 a1 = *(const uint4*)(PS + (size_t)(rowb + 16 + lp) * CCH + k0 + g * 8);
        short8 af[2] = {u4_to_s8(a0), u4_to_s8(a1)};
        short8 b[4];
#pragma unroll
        for (int t = 0; t < 4; ++t) {
            uint4 bw = *(const uint4*)(wsb + (size_t)(cob + t * 16 + lp) * 256 + k0 + g * 8);
            b[t] = u4_to_s8(bw);
        }
#pragma unroll
        for (int m = 0; m < 2; ++m)
#pragma unroll
            for (int t = 0; t < 4; ++t)
                acc[m][t] = __builtin_amdgcn_mfma_f32_16x16x32_bf16(af[m], b[t], acc[m][t], 0, 0, 0);
    }
#pragma unroll
    for (int m = 0; m < 2; ++m)
#pragma unroll
        for (int t = 0; t < 4; ++t) {
            int co = cob + t * 16 + lp;
            int h = co >> 5, d = co & 31;
            float bv = bs[co];
#pragma unroll
            for (int r = 0; r < 4; ++r) {
                int row = rowb + m * 16 + g * 4 + r;
                int zz = row >> 9, fb = (row >> 8) & 1, s = row & 255;
                int scc = zz / 5, kk = zz % 5;
                int slot = kk * 512 + fb * 256 + s;
                float val = acc[m][t][r] * inv[row] + bv;
                Csbf[(((size_t)scc * NH + h) * M2 + slot) * 32 + d] = f2bfu(val);
            }
        }
}

// ---------------- Q GEMM (img 0 only) ----------------
__global__ __launch_bounds__(512) void q_gemm(
        const float* __restrict__ x0, const float* __restrict__ x1,
        const float* __restrict__ x2, const float* __restrict__ x3,
        const uint16_t* __restrict__ WB, const float* __restrict__ bq,
        uint16_t* __restrict__ Qbf) {
    int sc = blockIdx.y;
    const float* xim = (sc == 0) ? x0 : (sc == 1) ? x1 : (sc == 2) ? x2 : x3;  // img 0
    int p0 = blockIdx.x * 64;
    int tid = threadIdx.x, lane = tid & 63, wid = tid >> 6;
    int lp = lane & 15, g = lane >> 4;
    int wm = wid >> 1, wn = wid & 1;
    __shared__ uint32_t Al[16][68];
    f32x4 acc[8] = {};
#pragma unroll
    for (int ks = 0; ks < 8; ++ks) {
        int k0 = ks * 32;
        __syncthreads();
        if (tid < 256) {
            int rp = tid >> 4, f4i = tid & 15;
            float4 v0 = *(const float4*)(xim + (size_t)(k0 + 2 * rp) * NPIX + p0 + f4i * 4);
            float4 v1 = *(const float4*)(xim + (size_t)(k0 + 2 * rp + 1) * NPIX + p0 + f4i * 4);
            *(uint4*)&Al[rp][f4i * 4] = make_uint4(
                pack_bf2(v0.x, v1.x), pack_bf2(v0.y, v1.y),
                pack_bf2(v0.z, v1.z), pack_bf2(v0.w, v1.w));
        }
        __syncthreads();
        short8 b[8];
#pragma unroll
        for (int tn = 0; tn < 8; ++tn) {
            uint4 bw = *(const uint4*)(WB + (size_t)(wn * 128 + tn * 16 + lp) * 256 + k0 + g * 8);
            b[tn] = u4_to_s8(bw);
        }
        int px = wm * 16 + lp;
        uint4 av = make_uint4(Al[4 * g + 0][px], Al[4 * g + 1][px],
                              Al[4 * g + 2][px], Al[4 * g + 3][px]);
        short8 af = u4_to_s8(av);
#pragma unroll
        for (int tn = 0; tn < 8; ++tn)
            acc[tn] = __builtin_amdgcn_mfma_f32_16x16x32_bf16(af, b[tn], acc[tn], 0, 0, 0);
    }
#pragma unroll
    for (int tn = 0; tn < 8; ++tn) {
        int co = wn * 128 + tn * 16 + lp;
        float bv = bq[co];
#pragma unroll
        for (int r = 0; r < 4; ++r) {
            int row = p0 + wm * 16 + g * 4 + r;
            Qbf[((size_t)(sc * NPIX + row)) * CCH + co] = f2bfu((acc[tn][r] + bv) * LOG2E);
        }
    }
}

// ---------------- attention v6: v4 structure + multiplicative mask (zero C-init, fmac) ------
// grid (16 px-tiles of 256, 8 heads, 16 = sc*4+split). 4 waves x 64px (4 Q-frags each).
__global__ __launch_bounds__(256) void attn_v6(
        const uint16_t* __restrict__ Qbf, const uint16_t* __restrict__ Csbf,
        const float* __restrict__ mexpb, float* __restrict__ sfbuf) {
    int head = blockIdx.y;
    int sc = blockIdx.z >> 2, split = blockIdx.z & 3;
    int tid = threadIdx.x;
    int lane = tid & 63, wid = tid >> 6;
    int lp = lane & 15, g = lane >> 4;
    int p0w = blockIdx.x * 256 + wid * 64;

    const uint16_t* Qs = Qbf + (size_t)sc * NPIX * CCH;
    const uint16_t* csb = Csbf + ((size_t)sc * NH + head) * M2 * 32;
    const float* mb = mexpb + sc * M2;

    short8 aq[4];
#pragma unroll
    for (int m = 0; m < 4; m++) {
        uint4 qv = *(const uint4*)(Qs + (size_t)(p0w + m * 16 + lp) * CCH + head * 32 + g * 8);
        aq[m] = u4_to_s8(qv);
    }

    const f32x4 zero4 = {0.f, 0.f, 0.f, 0.f};
    float sfg[4][4] = {}, sbg[4][4] = {};
    int cbeg = split * 640;
    for (int c0loc = 0; c0loc < 640; c0loc += 64) {
        int c0 = cbeg + c0loc;
        bool fg = ((c0 & 511) < 256);   // uniform per 64-chunk
        short8 bf[4];
        float mexp[4];
#pragma unroll
        for (int t = 0; t < 4; t++) {
            int row = c0 + t * 16 + lp;
            bf[t] = u4_to_s8(*(const uint4*)(csb + (size_t)row * 32 + g * 8));
            mexp[t] = mb[row];                 // 1.0 (live) or 0.0 (masked)
        }
        if (fg) {
#pragma unroll
            for (int m = 0; m < 4; m++)
#pragma unroll
                for (int t = 0; t < 4; t++) {
                    f32x4 c = __builtin_amdgcn_mfma_f32_16x16x32_bf16(aq[m], bf[t], zero4, 0, 0, 0);
#pragma unroll
                    for (int r = 0; r < 4; r++)
                        sfg[m][r] = fmaf(__builtin_amdgcn_exp2f(c[r]), mexp[t], sfg[m][r]);
                }
        } else {
#pragma unroll
            for (int m = 0; m < 4; m++)
#pragma unroll
                for (int t = 0; t < 4; t++) {
                    f32x4 c = __builtin_amdgcn_mfma_f32_16x16x32_bf16(aq[m], bf[t], zero4, 0, 0, 0);
#pragma unroll
                    for (int r = 0; r < 4; r++)
                        sbg[m][r] = fmaf(__builtin_amdgcn_exp2f(c[r]), mexp[t], sbg[m][r]);
                }
        }
    }
#pragma unroll
    for (int m = 0; m < 4; m++)
#pragma unroll
        for (int r = 0; r < 4; r++) {
#pragma unroll
            for (int msk = 1; msk < 16; msk <<= 1) {
                sfg[m][r] += __shfl_xor(sfg[m][r], msk);
                sbg[m][r] += __shfl_xor(sbg[m][r], msk);
            }
        }
    if (lp == 0) {
        float* sf = sfbuf + (size_t)((sc * 4 + split) * 2) * NH * NPIX;
        float* so = sf + (size_t)head * NPIX;
        float* fo = sf + (size_t)(NH + head) * NPIX;
#pragma unroll
        for (int m = 0; m < 4; m++)
#pragma unroll
            for (int r = 0; r < 4; r++) {
                int px = p0w + m * 16 + g * 4 + r;
                so[px] = sfg[m][r] + sbg[m][r];
                fo[px] = sfg[m][r];
            }
    }
}

// ---------------- head mean over 4 split partials ----------------
__global__ void mean_heads3(const float* __restrict__ sfbuf, float* __restrict__ cm) {
    int idx = blockIdx.x * 256 + threadIdx.x;   // 16384
    int sc = idx >> 12, p = idx & 4095;
    const float* b = sfbuf + (size_t)sc * 4 * 2 * NH * NPIX;
    float acc = 0.f;
#pragma unroll
    for (int h = 0; h < NH; h++) {
        float sv = 0.f, fv = 0.f;
#pragma unroll
        for (int sp = 0; sp < 4; sp++) {
            sv += b[((size_t)(sp * 2) * NH + h) * NPIX + p];
            fv += b[((size_t)(sp * 2 + 1) * NH + h) * NPIX + p];
        }
        acc += fv / sv;
    }
    cm[idx] = 0.125f * acc;
}

// ---------------- implicit-GEMM conv via MFMA ----------------
template<int CIN, int COUT, int KSZ>
__global__ __launch_bounds__(256) void conv_mfma(
        const float* __restrict__ in, const uint16_t* __restrict__ Wk,
        const float* __restrict__ bias, float* __restrict__ out) {
    constexpr int PAD = KSZ / 2;
    constexpr int NTAP = KSZ * KSZ;
    constexpr int K = CIN * NTAP;
    constexpr int CK = (K + 31) / 32;
    constexpr int PXP = 64 + 2 * PAD;
    constexpr int ICB = (CIN >= 8) ? CIN / 8 : 1;
    __shared__ uint16_t Xs[KSZ * PXP * CIN];
    int tid = threadIdx.x;
    int lane = tid & 63, wv = tid >> 6;
    int lp = lane & 15, g = lane >> 4;
    int y = blockIdx.x;
    int oc0 = blockIdx.y * 64;

    if (CIN >= 8) {
        for (int idx = tid; idx < KSZ * ICB * PXP; idx += 256) {
            int pxp = idx % PXP; int rem = idx / PXP;
            int icb = rem % ICB; int r = rem / ICB;
            int gy = y + r - PAD, gx = pxp - PAD;
            bool ok = ((unsigned)gy < 64u) && ((unsigned)gx < 64u);
            const float* ip = in + (size_t)(icb * 8) * NPIX + gy * 64 + gx;
            uint32_t wb[4];
#pragma unroll
            for (int j = 0; j < 4; j++) {
                float v0 = ok ? ip[(size_t)(2 * j) * NPIX] : 0.f;
                float v1 = ok ? ip[(size_t)(2 * j + 1) * NPIX] : 0.f;
                wb[j] = pack_bf2(v0, v1);
            }
            *(uint4*)&Xs[(size_t)idx * 8] = make_uint4(wb[0], wb[1], wb[2], wb[3]);
        }
    } else {
        for (int idx = tid; idx < KSZ * PXP; idx += 256) {
            int pxp = idx % PXP; int r = idx / PXP;
            int gy = y + r - PAD, gx = pxp - PAD;
            bool ok = ((unsigned)gy < 64u) && ((unsigned)gx < 64u);
            const float* ip = in + (size_t)gy * 64 + gx;
            float v0 = ok ? ip[0] : 0.f, v1 = ok ? ip[NPIX] : 0.f;
            float v2 = ok ? ip[2 * NPIX] : 0.f, v3 = ok ? ip[3 * NPIX] : 0.f;
            *(uint2*)&Xs[(size_t)idx * 4] = make_uint2(pack_bf2(v0, v1), pack_bf2(v2, v3));
        }
    }
    __syncthreads();

    int tmb, tme, tn;
    if (COUT >= 64) { tn = wv; tmb = 0; tme = 4; }
    else            { tn = 0;  tmb = wv; tme = wv + 1; }
    int oc = oc0 + tn * 16 + lp;
    f32x4 acc[4] = {};

#pragma unroll
    for (int ck = 0; ck < CK; ck++) {
        const uint16_t* wp = Wk + ((size_t)ck * COUT + oc) * 32 + g * 8;
        uint4 bw = *(const uint4*)wp;
        short8 bfr = u4_to_s8(bw);
        if (CIN >= 8) {
            int gk = ck * 4 + g;
            int tap = gk / ICB; if (tap > NTAP - 1) tap = NTAP - 1;
            int icb = gk % ICB;
            int r = tap / KSZ, dx = tap % KSZ;
            int base = (r * ICB + icb) * PXP * 8;
            for (int tm = tmb; tm < tme; tm++) {
                int pxp = tm * 16 + lp + dx;
                uint4 av = *(const uint4*)&Xs[base + pxp * 8];
                short8 afr = u4_to_s8(av);
                acc[tm] = __builtin_amdgcn_mfma_f32_16x16x32_bf16(afr, bfr, acc[tm], 0, 0, 0);
            }
        } else {
            int gk = ck * 4 + g;
            int t0 = 2 * gk;     if (t0 > NTAP - 1) t0 = NTAP - 1;
            int t1 = 2 * gk + 1; if (t1 > NTAP - 1) t1 = NTAP - 1;
            int r0 = t0 / KSZ, dx0 = t0 % KSZ;
            int r1 = t1 / KSZ, dx1 = t1 % KSZ;
            for (int tm = tmb; tm < tme; tm++) {
                uint2 a0 = *(const uint2*)&Xs[((size_t)(r0 * PXP + tm * 16 + lp + dx0)) * 4];
                uint2 a1 = *(const uint2*)&Xs[((size_t)(r1 * PXP + tm * 16 + lp + dx1)) * 4];
                uint4 av = make_uint4(a0.x, a0.y, a1.x, a1.y);
                short8 afr = u4_to_s8(av);
                acc[tm] = __builtin_amdgcn_mfma_f32_16x16x32_bf16(afr, bfr, acc[tm], 0, 0, 0);
            }
        }
    }
    float bv = bias[oc];
    for (int tm = tmb; tm < tme; tm++)
#pragma unroll
        for (int r = 0; r < 4; r++) {
            int px = tm * 16 + g * 4 + r;
            out[(size_t)oc * NPIX + y * 64 + px] = acc[tm][r] + bv;
        }
}

// ---------------- group norm: stage 1 partial sums ----------------
__global__ __launch_bounds__(256) void gn_part(const float* __restrict__ in, int Cg,
                                               float* __restrict__ part) {
    int g = blockIdx.x, b = blockIdx.y;
    int n4 = Cg * 1024;
    const float4* base = (const float4*)(in + (size_t)g * Cg * NPIX);
    float s = 0.0f, s2 = 0.0f;
    for (int i = b * 256 + threadIdx.x; i < n4; i += GN_NB * 256) {
        float4 v = base[i];
        s += v.x + v.y + v.z + v.w;
        s2 = fmaf(v.x, v.x, s2); s2 = fmaf(v.y, v.y, s2);
        s2 = fmaf(v.z, v.z, s2); s2 = fmaf(v.w, v.w, s2);
    }
#pragma unroll
    for (int off = 32; off; off >>= 1) {
        s += __shfl_down(s, off);
        s2 += __shfl_down(s2, off);
    }
    __shared__ float rs[4], rs2[4];
    int w = threadIdx.x >> 6;
    if ((threadIdx.x & 63) == 0) { rs[w] = s; rs2[w] = s2; }
    __syncthreads();
    if (threadIdx.x == 0) {
        part[(g * GN_NB + b) * 2]     = rs[0] + rs[1] + rs[2] + rs[3];
        part[(g * GN_NB + b) * 2 + 1] = rs2[0] + rs2[1] + rs2[2] + rs2[3];
    }
}

// ---------------- group norm: stage 2 apply + relu ----------------
__global__ __launch_bounds__(256) void gn_apply_relu(const float* __restrict__ in, const float* __restrict__ part,
                                                     const float* __restrict__ gamma, const float* __restrict__ beta,
                                                     int Cg, float* __restrict__ out) {
    int idx4 = blockIdx.x * 256 + threadIdx.x;
    int c = idx4 >> 10;
    int g = c / Cg;
    float s = 0.0f, s2 = 0.0f;
#pragma unroll
    for (int b = 0; b < GN_NB; b++) {
        s  += part[(g * GN_NB + b) * 2];
        s2 += part[(g * GN_NB + b) * 2 + 1];
    }
    float n = (float)(Cg * NPIX);
    float mu = s / n;
    float rstd = rsqrtf(s2 / n - mu * mu + 1e-5f);
    float ga = gamma[c] * rstd;
    float be = beta[c] - mu * ga;
    float4 v = ((const float4*)in)[idx4];
    float4 o;
    o.x = fmaf(v.x, ga, be); o.x = o.x > 0.f ? o.x : 0.f;
    o.y = fmaf(v.y, ga, be); o.y = o.y > 0.f ? o.y : 0.f;
    o.z = fmaf(v.z, ga, be); o.z = o.z > 0.f ? o.z : 0.f;
    o.w = fmaf(v.w, ga, be); o.w = o.w > 0.f ? o.w : 0.f;
    ((float4*)out)[idx4] = o;
}

// ---------------- launch ----------------
extern "C" void kernel_launch(void* const* d_in, const int* in_sizes, int n_in,
                              void* d_out, int out_size, void* d_ws, size_t ws_size,
                              hipStream_t stream) {
    const float* x0 = (const float*)d_in[0];
    const float* x1 = (const float*)d_in[1];
    const float* x2 = (const float*)d_in[2];
    const float* x3 = (const float*)d_in[3];
    const float* dox = (const float*)d_in[4];
    const float* wq  = (const float*)d_in[5];
    const float* bq  = (const float*)d_in[6];
    const float* wsm = (const float*)d_in[7];
    const float* bs  = (const float*)d_in[8];
    const float* cw1 = (const float*)d_in[9];
    const float* cb1 = (const float*)d_in[10];
    const float* g1  = (const float*)d_in[11];
    const float* be1 = (const float*)d_in[12];
    const float* cw2 = (const float*)d_in[13];
    const float* cb2 = (const float*)d_in[14];
    const float* g2  = (const float*)d_in[15];
    const float* be2 = (const float*)d_in[16];
    const float* cw3 = (const float*)d_in[17];
    const float* cb3 = (const float*)d_in[18];
    const float* g3  = (const float*)d_in[19];
    const float* be3 = (const float*)d_in[20];

    // u16 region
    uint16_t* Qbf  = (uint16_t*)d_ws;                        // 4194304
    uint16_t* Csbf = Qbf + (size_t)4194304;                  // 2621440
    uint16_t* PS   = Csbf + (size_t)2621440;                 // 2621440
    uint16_t* WB   = PS + (size_t)2621440;                   // 131072
    uint16_t* Wk1  = WB + 131072;                            // 2048
    uint16_t* Wk2  = Wk1 + 2048;                             // 26624
    uint16_t* Wk3  = Wk2 + 26624;                            // 73728
    // float region
    float* fbase  = (float*)(Wk3 + 73728);
    float* mexpb  = fbase;                 // 10240
    float* inv    = mexpb + 10240;         // 10240
    float* sfbuf  = inv + 10240;           // 1048576
    float* cm     = sfbuf + 1048576;       // 16384
    float* h1     = cm + 16384;            // 65536
    float* h2     = h1 + 65536;            // 262144
    float* h3     = h2 + 262144;           // 524288
    float* gnpart = h3 + 524288;           // 256

    // fused prepack (WB + Wk1..3): 131072+2048+26624+73728 = 233472 elems
    prep_all<<<(233472 + 255) / 256, 256, 0, stream>>>(wq, wsm, cw1, cw2, cw3, WB, Wk1, Wk2, Wk3);

    // pipeline
    patch_sum<<<dim3(16, 4, 20), 256, 0, stream>>>(x0, x1, x2, x3, dox, PS, inv, mexpb);
    q_gemm<<<dim3(64, 4), 512, 0, stream>>>(x0, x1, x2, x3, WB, bq, Qbf);
    cent_gemm<<<dim3(80, 4), 256, 0, stream>>>(PS, WB, bs, inv, Csbf);
    attn_v6<<<dim3(16, NH, 16), 256, 0, stream>>>(Qbf, Csbf, mexpb, sfbuf);
    mean_heads3<<<64, 256, 0, stream>>>(sfbuf, cm);

    conv_mfma<4, 16, 5><<<dim3(64, 1), 256, 0, stream>>>(cm, Wk1, cb1, h1);
    gn_part<<<dim3(4, GN_NB), 256, 0, stream>>>(h1, 4, gnpart);
    gn_apply_relu<<<(16 * 1024) / 256, 256, 0, stream>>>(h1, gnpart, g1, be1, 4, h1);

    conv_mfma<16, 64, 5><<<dim3(64, 1), 256, 0, stream>>>(h1, Wk2, cb2, h2);
    gn_part<<<dim3(4, GN_NB), 256, 0, stream>>>(h2, 16, gnpart);
    gn_apply_relu<<<(64 * 1024) / 256, 256, 0, stream>>>(h2, gnpart, g2, be2, 16, h2);

    conv_mfma<64, 128, 3><<<dim3(64, 2), 256, 0, stream>>>(h2, Wk3, cb3, h3);
    gn_part<<<dim3(4, GN_NB), 256, 0, stream>>>(h3, 32, gnpart);
    gn_apply_relu<<<(128 * 1024) / 256, 256, 0, stream>>>(h3, gnpart, g3, be3, 32, (float*)d_out);
}

// Round 14
// 144.353 us; speedup vs baseline: 1.0644x; 1.0201x over previous
//
#include <hip/hip_runtime.h>
#include <hip/hip_bf16.h>
#include <stdint.h>

#define CCH 256
#define NPIX 4096      // 64*64
#define NH 8
#define M2 2560        // K*2*S
#define LOG2E 1.44269504088896f
#define GN_NB 32

typedef __attribute__((ext_vector_type(8))) short short8;
typedef __attribute__((ext_vector_type(4))) float f32x4;

__device__ __forceinline__ uint16_t f2bfu(float f) {
    uint32_t u = __builtin_bit_cast(uint32_t, f);
    return (uint16_t)((u + 0x7FFFu + ((u >> 16) & 1u)) >> 16);   // RNE
}
__device__ __forceinline__ uint32_t pack_bf2(float a, float b) {
    return (uint32_t)f2bfu(a) | ((uint32_t)f2bfu(b) << 16);
}
__device__ __forceinline__ short8 u4_to_s8(uint4 v) {
    return __builtin_bit_cast(short8, v);
}

// ---------------- fused prepack: WB (feature weights) + conv Wk1/Wk2/Wk3 ----------------
__device__ __forceinline__ void prep_w_one(const float* __restrict__ w, uint16_t* __restrict__ Wk,
                                           int idx, int Cin, int Cout, int K2) {
    int kk = idx & 31;
    int oc = (idx >> 5) % Cout;
    int ck = idx / (32 * Cout);
    int k = ck * 32 + kk;
    int tap = k / Cin, ic = k % Cin;
    float v = (tap < K2) ? w[((size_t)oc * Cin + ic) * K2 + tap] : 0.0f;
    Wk[idx] = f2bfu(v);
}

__global__ void prep_all(const float* __restrict__ wq, const float* __restrict__ wsm,
                         const float* __restrict__ cw1, const float* __restrict__ cw2,
                         const float* __restrict__ cw3,
                         uint16_t* __restrict__ WB, uint16_t* __restrict__ Wk1,
                         uint16_t* __restrict__ Wk2, uint16_t* __restrict__ Wk3) {
    int idx = blockIdx.x * 256 + threadIdx.x;
    if (idx < 131072) {                       // WB: wq|wsm -> bf16
        const float* src = (idx < 65536) ? wq : wsm;
        WB[idx] = f2bfu(src[idx & 65535]);
        return;
    }
    idx -= 131072;
    if (idx < 2048)  { prep_w_one(cw1, Wk1, idx, 4, 16, 25);  return; }
    idx -= 2048;
    if (idx < 26624) { prep_w_one(cw2, Wk2, idx, 16, 64, 25); return; }
    idx -= 26624;
    if (idx < 73728) { prep_w_one(cw3, Wk3, idx, 64, 128, 9); return; }
}

// ---------------- patch-weighted sums of x (linearity: centroids = W.psum/fgs + b) ----------
__global__ __launch_bounds__(256) void patch_sum(
        const float* __restrict__ x0, const float* __restrict__ x1,
        const float* __restrict__ x2, const float* __restrict__ x3,
        const float* __restrict__ dox, uint16_t* __restrict__ PS,
        float* __restrict__ inv, float* __restrict__ mexpb) {
    int z = blockIdx.z;
    int sc = z / 5, k = z % 5;
    const float* xim = ((sc == 0) ? x0 : (sc == 1) ? x1 : (sc == 2) ? x2 : x3)
                       + (size_t)(k + 1) * CCH * NPIX;    // s-images 1..5
    int p1 = blockIdx.x, chq = blockIdx.y;
    int tid = threadIdx.x;
    int cloc = tid >> 6, col = tid & 63;
    __shared__ float wls[4][64];
    __shared__ uint16_t pst[2][16][72];
    wls[cloc][col] = dox[(size_t)k * 65536 + (size_t)(16 * p1 + 4 * cloc) * 256 + 4 * col];
    __syncthreads();
    float w0 = wls[0][col], w1 = wls[1][col], w2 = wls[2][col], w3 = wls[3][col];
    const float* xbase = xim + p1 * 256 + col;
#pragma unroll 4
    for (int it = 0; it < 16; ++it) {
        int c = chq * 64 + it * 4 + cloc;
        const float* xp = xbase + (size_t)c * NPIX;
        float v0 = xp[0], v1 = xp[64], v2 = xp[128], v3 = xp[192];
        float pf = w0 * v0 + w1 * v1 + w2 * v2 + w3 * v3;
        float pb = (v0 + v1 + v2 + v3) - pf;
        pf += __shfl_xor(pf, 1); pf += __shfl_xor(pf, 2);
        pb += __shfl_xor(pb, 1); pb += __shfl_xor(pb, 2);
        if ((col & 3) == 0) {
            int q = col >> 2, cl = it * 4 + cloc;
            pst[0][q][cl] = f2bfu(pf);
            pst[1][q][cl] = f2bfu(pb);
        }
    }
    if (chq == 0 && tid < 64) {
        float ws = w0 + w1 + w2 + w3;
        ws += __shfl_xor(ws, 1); ws += __shfl_xor(ws, 2);
        if ((col & 3) == 0) {
            int s = p1 * 16 + (col >> 2);
            float fsum = ws, bsum = 16.f - ws;
            int mf = k * 512 + s, mbk = mf + 256;
            mexpb[sc * M2 + mf]  = (fsum < 1.f) ? 0.f : 1.f;   // multiplicative mask
            mexpb[sc * M2 + mbk] = (bsum < 1.f) ? 0.f : 1.f;
            inv[(size_t)(z * 2 + 0) * 256 + s] = 1.f / fmaxf(fsum, 1e-6f);
            inv[(size_t)(z * 2 + 1) * 256 + s] = 1.f / fmaxf(bsum, 1e-6f);
        }
    }
    __syncthreads();
    int fb = tid >> 7, rem = tid & 127;
    int q = rem >> 3, chunk = rem & 7;
    uint4 v = *(const uint4*)&pst[fb][q][chunk * 8];
    int s = p1 * 16 + q;
    *(uint4*)&PS[((size_t)(z * 2 + fb) * 256 + s) * CCH + chq * 64 + chunk * 8] = v;
}

// ---------------- centroid GEMM: Cs = W.(psum)*inv + b ----------------
__global__ __launch_bounds__(256) void cent_gemm(
        const uint16_t* __restrict__ PS, const uint16_t* __restrict__ WB,
        const float* __restrict__ bs, const float* __restrict__ inv,
        uint16_t* __restrict__ Csbf) {
    int tid = threadIdx.x, lane = tid & 63, wid = tid >> 6;
    int lp = lane & 15, g = lane >> 4;
    int rowb = blockIdx.x * 128 + wid * 32;
    int cob = blockIdx.y * 64;
    const uint16_t* wsb = WB + 65536;
    f32x4 acc[2][4] = {};
#pragma unroll
    for (int ks = 0; ks < 8; ++ks) {
        int k0 = ks * 32;
        uint4 a0 = *(const uint4*)(PS + (size_t)(rowb + lp) * CCH + k0 + g * 8);
        uint4 a1 = *(const uint4*)(PS + (size_t)(rowb + 16 + lp) * CCH + k0 + g * 8);
        short8 af[2] = {u4_to_s8(a0), u4_to_s8(a1)};
        short8 b[4];
#pragma unroll
        for (int t = 0; t < 4; ++t) {
            uint4 bw = *(const uint4*)(wsb + (size_t)(cob + t * 16 + lp) * 256 + k0 + g * 8);
            b[t] = u4_to_s8(bw);
        }
#pragma unroll
        for (int m = 0; m < 2; ++m)
#pragma unroll
            for (int t = 0; t < 4; ++t)
                acc[m][t] = __builtin_amdgcn_mfma_f32_16x16x32_bf16(af[m], b[t], acc[m][t], 0, 0, 0);
    }
#pragma unroll
    for (int m = 0; m < 2; ++m)
#pragma unroll
        for (int t = 0; t < 4; ++t) {
            int co = cob + t * 16 + lp;
            int h = co >> 5, d = co & 31;
            float bv = bs[co];
#pragma unroll
            for (int r = 0; r < 4; ++r) {
                int row = rowb + m * 16 + g * 4 + r;
                int zz = row >> 9, fb = (row >> 8) & 1, s = row & 255;
                int scc = zz / 5, kk = zz % 5;
                int slot = kk * 512 + fb * 256 + s;
                float val = acc[m][t][r] * inv[row] + bv;
                Csbf[(((size_t)scc * NH + h) * M2 + slot) * 32 + d] = f2bfu(val);
            }
        }
}

// ---------------- Q GEMM (img 0 only) ----------------
__global__ __launch_bounds__(512) void q_gemm(
        const float* __restrict__ x0, const float* __restrict__ x1,
        const float* __restrict__ x2, const float* __restrict__ x3,
        const uint16_t* __restrict__ WB, const float* __restrict__ bq,
        uint16_t* __restrict__ Qbf) {
    int sc = blockIdx.y;
    const float* xim = (sc == 0) ? x0 : (sc == 1) ? x1 : (sc == 2) ? x2 : x3;  // img 0
    int p0 = blockIdx.x * 64;
    int tid = threadIdx.x, lane = tid & 63, wid = tid >> 6;
    int lp = lane & 15, g = lane >> 4;
    int wm = wid >> 1, wn = wid & 1;
    __shared__ uint32_t Al[16][68];
    f32x4 acc[8] = {};
#pragma unroll
    for (int ks = 0; ks < 8; ++ks) {
        int k0 = ks * 32;
        __syncthreads();
        if (tid < 256) {
            int rp = tid >> 4, f4i = tid & 15;
            float4 v0 = *(const float4*)(xim + (size_t)(k0 + 2 * rp) * NPIX + p0 + f4i * 4);
            float4 v1 = *(const float4*)(xim + (size_t)(k0 + 2 * rp + 1) * NPIX + p0 + f4i * 4);
            *(uint4*)&Al[rp][f4i * 4] = make_uint4(
                pack_bf2(v0.x, v1.x), pack_bf2(v0.y, v1.y),
                pack_bf2(v0.z, v1.z), pack_bf2(v0.w, v1.w));
        }
        __syncthreads();
        short8 b[8];
#pragma unroll
        for (int tn = 0; tn < 8; ++tn) {
            uint4 bw = *(const uint4*)(WB + (size_t)(wn * 128 + tn * 16 + lp) * 256 + k0 + g * 8);
            b[tn] = u4_to_s8(bw);
        }
        int px = wm * 16 + lp;
        uint4 av = make_uint4(Al[4 * g + 0][px], Al[4 * g + 1][px],
                              Al[4 * g + 2][px], Al[4 * g + 3][px]);
        short8 af = u4_to_s8(av);
#pragma unroll
        for (int tn = 0; tn < 8; ++tn)
            acc[tn] = __builtin_amdgcn_mfma_f32_16x16x32_bf16(af, b[tn], acc[tn], 0, 0, 0);
    }
#pragma unroll
    for (int tn = 0; tn < 8; ++tn) {
        int co = wn * 128 + tn * 16 + lp;
        float bv = bq[co];
#pragma unroll
        for (int r = 0; r < 4; ++r) {
            int row = p0 + wm * 16 + g * 4 + r;
            Qbf[((size_t)(sc * NPIX + row)) * CCH + co] = f2bfu((acc[tn][r] + bv) * LOG2E);
        }
    }
}

// ---------------- attention v7: LDS-staged Cs (shared by 4 waves), dbuf + issue-early ----------
// grid (16 px-tiles of 256, 8 heads, 16 = sc*4+split). 4 waves x 64px (4 Q-frags each).
// LDS chunk layout: Cl[buf][r][j] (16B units) = Cs[c0+r][j ^ (r&3)]  (source-side swizzle,
// linear LDS writes; read addr uses the same XOR -> 4-way max bank aliasing).
__global__ __launch_bounds__(256) void attn_v7(
        const uint16_t* __restrict__ Qbf, const uint16_t* __restrict__ Csbf,
        const float* __restrict__ mexpb, float* __restrict__ sfbuf) {
    int head = blockIdx.y;
    int sc = blockIdx.z >> 2, split = blockIdx.z & 3;
    int tid = threadIdx.x;
    int lane = tid & 63, wid = tid >> 6;
    int lp = lane & 15, g = lane >> 4;
    int p0w = blockIdx.x * 256 + wid * 64;

    __shared__ uint16_t Cl[2][2048];   // 2 x 4KB chunk buffers

    const uint16_t* Qs = Qbf + (size_t)sc * NPIX * CCH;
    const uint16_t* csb = Csbf + ((size_t)sc * NH + head) * M2 * 32;
    const float* mb = mexpb + sc * M2;

    short8 aq[4];
#pragma unroll
    for (int m = 0; m < 4; m++) {
        uint4 qv = *(const uint4*)(Qs + (size_t)(p0w + m * 16 + lp) * CCH + head * 32 + g * 8);
        aq[m] = u4_to_s8(qv);
    }

    // staging geometry: thread tid handles LDS unit (sr, sq4); global src unit swizzled
    int sr = tid >> 2, sq4 = tid & 3;
    int ssw = sq4 ^ (sr & 3);
    int cbeg = split * 640;
    const uint16_t* sgp = csb + ((size_t)(cbeg + sr)) * 32 + ssw * 8;
    const int ldst_off = sr * 32 + sq4 * 8;   // u16 units

    const f32x4 zero4 = {0.f, 0.f, 0.f, 0.f};
    float sfg[4][4] = {}, sbg[4][4] = {};

    // prologue: stage chunk 0 into buf 0
    {
        uint4 gv = *(const uint4*)sgp;
        *(uint4*)(&Cl[0][ldst_off]) = gv;
    }
    __syncthreads();

    for (int ci = 0; ci < 10; ci++) {
        int c0 = cbeg + ci * 64;
        bool fg = ((c0 & 511) < 256);   // uniform per 64-chunk
        // issue next chunk's global load EARLY (consumed by ds_write after compute)
        uint4 ngv;
        if (ci < 9) ngv = *(const uint4*)(sgp + (size_t)(ci + 1) * 64 * 32);

        const uint16_t* lbuf = &Cl[ci & 1][0];
        short8 bf[4];
        float mexp[4];
#pragma unroll
        for (int t = 0; t < 4; t++) {
            int r = t * 16 + lp;
            bf[t] = u4_to_s8(*(const uint4*)(lbuf + r * 32 + ((g ^ (lp & 3)) * 8)));
            mexp[t] = mb[c0 + r];                 // 1.0 (live) or 0.0 (masked)
        }
        if (fg) {
#pragma unroll
            for (int m = 0; m < 4; m++)
#pragma unroll
                for (int t = 0; t < 4; t++) {
                    f32x4 c = __builtin_amdgcn_mfma_f32_16x16x32_bf16(aq[m], bf[t], zero4, 0, 0, 0);
#pragma unroll
                    for (int r = 0; r < 4; r++)
                        sfg[m][r] = fmaf(__builtin_amdgcn_exp2f(c[r]), mexp[t], sfg[m][r]);
                }
        } else {
#pragma unroll
            for (int m = 0; m < 4; m++)
#pragma unroll
                for (int t = 0; t < 4; t++) {
                    f32x4 c = __builtin_amdgcn_mfma_f32_16x16x32_bf16(aq[m], bf[t], zero4, 0, 0, 0);
#pragma unroll
                    for (int r = 0; r < 4; r++)
                        sbg[m][r] = fmaf(__builtin_amdgcn_exp2f(c[r]), mexp[t], sbg[m][r]);
                }
        }
        // write-late: ds_write the prefetched chunk, then one barrier
        if (ci < 9) {
            *(uint4*)(&Cl[(ci + 1) & 1][ldst_off]) = ngv;
        }
        __syncthreads();
    }
#pragma unroll
    for (int m = 0; m < 4; m++)
#pragma unroll
        for (int r = 0; r < 4; r++) {
#pragma unroll
            for (int msk = 1; msk < 16; msk <<= 1) {
                sfg[m][r] += __shfl_xor(sfg[m][r], msk);
                sbg[m][r] += __shfl_xor(sbg[m][r], msk);
            }
        }
    if (lp == 0) {
        float* sf = sfbuf + (size_t)((sc * 4 + split) * 2) * NH * NPIX;
        float* so = sf + (size_t)head * NPIX;
        float* fo = sf + (size_t)(NH + head) * NPIX;
#pragma unroll
        for (int m = 0; m < 4; m++)
#pragma unroll
            for (int r = 0; r < 4; r++) {
                int px = p0w + m * 16 + g * 4 + r;
                so[px] = sfg[m][r] + sbg[m][r];
                fo[px] = sfg[m][r];
            }
    }
}

// ---------------- head mean over 4 split partials ----------------
__global__ void mean_heads3(const float* __restrict__ sfbuf, float* __restrict__ cm) {
    int idx = blockIdx.x * 256 + threadIdx.x;   // 16384
    int sc = idx >> 12, p = idx & 4095;
    const float* b = sfbuf + (size_t)sc * 4 * 2 * NH * NPIX;
    float acc = 0.f;
#pragma unroll
    for (int h = 0; h < NH; h++) {
        float sv = 0.f, fv = 0.f;
#pragma unroll
        for (int sp = 0; sp < 4; sp++) {
            sv += b[((size_t)(sp * 2) * NH + h) * NPIX + p];
            fv += b[((size_t)(sp * 2 + 1) * NH + h) * NPIX + p];
        }
        acc += fv / sv;
    }
    cm[idx] = 0.125f * acc;
}

// ---------------- implicit-GEMM conv via MFMA ----------------
template<int CIN, int COUT, int KSZ>
__global__ __launch_bounds__(256) void conv_mfma(
        const float* __restrict__ in, const uint16_t* __restrict__ Wk,
        const float* __restrict__ bias, float* __restrict__ out) {
    constexpr int PAD = KSZ / 2;
    constexpr int NTAP = KSZ * KSZ;
    constexpr int K = CIN * NTAP;
    constexpr int CK = (K + 31) / 32;
    constexpr int PXP = 64 + 2 * PAD;
    constexpr int ICB = (CIN >= 8) ? CIN / 8 : 1;
    __shared__ uint16_t Xs[KSZ * PXP * CIN];
    int tid = threadIdx.x;
    int lane = tid & 63, wv = tid >> 6;
    int lp = lane & 15, g = lane >> 4;
    int y = blockIdx.x;
    int oc0 = blockIdx.y * 64;

    if (CIN >= 8) {
        for (int idx = tid; idx < KSZ * ICB * PXP; idx += 256) {
            int pxp = idx % PXP; int rem = idx / PXP;
            int icb = rem % ICB; int r = rem / ICB;
            int gy = y + r - PAD, gx = pxp - PAD;
            bool ok = ((unsigned)gy < 64u) && ((unsigned)gx < 64u);
            const float* ip = in + (size_t)(icb * 8) * NPIX + gy * 64 + gx;
            uint32_t wb[4];
#pragma unroll
            for (int j = 0; j < 4; j++) {
                float v0 = ok ? ip[(size_t)(2 * j) * NPIX] : 0.f;
                float v1 = ok ? ip[(size_t)(2 * j + 1) * NPIX] : 0.f;
                wb[j] = pack_bf2(v0, v1);
            }
            *(uint4*)&Xs[(size_t)idx * 8] = make_uint4(wb[0], wb[1], wb[2], wb[3]);
        }
    } else {
        for (int idx = tid; idx < KSZ * PXP; idx += 256) {
            int pxp = idx % PXP; int r = idx / PXP;
            int gy = y + r - PAD, gx = pxp - PAD;
            bool ok = ((unsigned)gy < 64u) && ((unsigned)gx < 64u);
            const float* ip = in + (size_t)gy * 64 + gx;
            float v0 = ok ? ip[0] : 0.f, v1 = ok ? ip[NPIX] : 0.f;
            float v2 = ok ? ip[2 * NPIX] : 0.f, v3 = ok ? ip[3 * NPIX] : 0.f;
            *(uint2*)&Xs[(size_t)idx * 4] = make_uint2(pack_bf2(v0, v1), pack_bf2(v2, v3));
        }
    }
    __syncthreads();

    int tmb, tme, tn;
    if (COUT >= 64) { tn = wv; tmb = 0; tme = 4; }
    else            { tn = 0;  tmb = wv; tme = wv + 1; }
    int oc = oc0 + tn * 16 + lp;
    f32x4 acc[4] = {};

#pragma unroll
    for (int ck = 0; ck < CK; ck++) {
        const uint16_t* wp = Wk + ((size_t)ck * COUT + oc) * 32 + g * 8;
        uint4 bw = *(const uint4*)wp;
        short8 bfr = u4_to_s8(bw);
        if (CIN >= 8) {
            int gk = ck * 4 + g;
            int tap = gk / ICB; if (tap > NTAP - 1) tap = NTAP - 1;
            int icb = gk % ICB;
            int r = tap / KSZ, dx = tap % KSZ;
            int base = (r * ICB + icb) * PXP * 8;
            for (int tm = tmb; tm < tme; tm++) {
                int pxp = tm * 16 + lp + dx;
                uint4 av = *(const uint4*)&Xs[base + pxp * 8];
                short8 afr = u4_to_s8(av);
                acc[tm] = __builtin_amdgcn_mfma_f32_16x16x32_bf16(afr, bfr, acc[tm], 0, 0, 0);
            }
        } else {
            int gk = ck * 4 + g;
            int t0 = 2 * gk;     if (t0 > NTAP - 1) t0 = NTAP - 1;
            int t1 = 2 * gk + 1; if (t1 > NTAP - 1) t1 = NTAP - 1;
            int r0 = t0 / KSZ, dx0 = t0 % KSZ;
            int r1 = t1 / KSZ, dx1 = t1 % KSZ;
            for (int tm = tmb; tm < tme; tm++) {
                uint2 a0 = *(const uint2*)&Xs[((size_t)(r0 * PXP + tm * 16 + lp + dx0)) * 4];
                uint2 a1 = *(const uint2*)&Xs[((size_t)(r1 * PXP + tm * 16 + lp + dx1)) * 4];
                uint4 av = make_uint4(a0.x, a0.y, a1.x, a1.y);
                short8 afr = u4_to_s8(av);
                acc[tm] = __builtin_amdgcn_mfma_f32_16x16x32_bf16(afr, bfr, acc[tm], 0, 0, 0);
            }
        }
    }
    float bv = bias[oc];
    for (int tm = tmb; tm < tme; tm++)
#pragma unroll
        for (int r = 0; r < 4; r++) {
            int px = tm * 16 + g * 4 + r;
            out[(size_t)oc * NPIX + y * 64 + px] = acc[tm][r] + bv;
        }
}

// ---------------- group norm: stage 1 partial sums ----------------
__global__ __launch_bounds__(256) void gn_part(const float* __restrict__ in, int Cg,
                                               float* __restrict__ part) {
    int g = blockIdx.x, b = blockIdx.y;
    int n4 = Cg * 1024;
    const float4* base = (const float4*)(in + (size_t)g * Cg * NPIX);
    float s = 0.0f, s2 = 0.0f;
    for (int i = b * 256 + threadIdx.x; i < n4; i += GN_NB * 256) {
        float4 v = base[i];
        s += v.x + v.y + v.z + v.w;
        s2 = fmaf(v.x, v.x, s2); s2 = fmaf(v.y, v.y, s2);
        s2 = fmaf(v.z, v.z, s2); s2 = fmaf(v.w, v.w, s2);
    }
#pragma unroll
    for (int off = 32; off; off >>= 1) {
        s += __shfl_down(s, off);
        s2 += __shfl_down(s2, off);
    }
    __shared__ float rs[4], rs2[4];
    int w = threadIdx.x >> 6;
    if ((threadIdx.x & 63) == 0) { rs[w] = s; rs2[w] = s2; }
    __syncthreads();
    if (threadIdx.x == 0) {
        part[(g * GN_NB + b) * 2]     = rs[0] + rs[1] + rs[2] + rs[3];
        part[(g * GN_NB + b) * 2 + 1] = rs2[0] + rs2[1] + rs2[2] + rs2[3];
    }
}

// ---------------- group norm: stage 2 apply + relu ----------------
__global__ __launch_bounds__(256) void gn_apply_relu(const float* __restrict__ in, const float* __restrict__ part,
                                                     const float* __restrict__ gamma, const float* __restrict__ beta,
                                                     int Cg, float* __restrict__ out) {
    int idx4 = blockIdx.x * 256 + threadIdx.x;
    int c = idx4 >> 10;
    int g = c / Cg;
    float s = 0.0f, s2 = 0.0f;
#pragma unroll
    for (int b = 0; b < GN_NB; b++) {
        s  += part[(g * GN_NB + b) * 2];
        s2 += part[(g * GN_NB + b) * 2 + 1];
    }
    float n = (float)(Cg * NPIX);
    float mu = s / n;
    float rstd = rsqrtf(s2 / n - mu * mu + 1e-5f);
    float ga = gamma[c] * rstd;
    float be = beta[c] - mu * ga;
    float4 v = ((const float4*)in)[idx4];
    float4 o;
    o.x = fmaf(v.x, ga, be); o.x = o.x > 0.f ? o.x : 0.f;
    o.y = fmaf(v.y, ga, be); o.y = o.y > 0.f ? o.y : 0.f;
    o.z = fmaf(v.z, ga, be); o.z = o.z > 0.f ? o.z : 0.f;
    o.w = fmaf(v.w, ga, be); o.w = o.w > 0.f ? o.w : 0.f;
    ((float4*)out)[idx4] = o;
}

// ---------------- launch ----------------
extern "C" void kernel_launch(void* const* d_in, const int* in_sizes, int n_in,
                              void* d_out, int out_size, void* d_ws, size_t ws_size,
                              hipStream_t stream) {
    const float* x0 = (const float*)d_in[0];
    const float* x1 = (const float*)d_in[1];
    const float* x2 = (const float*)d_in[2];
    const float* x3 = (const float*)d_in[3];
    const float* dox = (const float*)d_in[4];
    const float* wq  = (const float*)d_in[5];
    const float* bq  = (const float*)d_in[6];
    const float* wsm = (const float*)d_in[7];
    const float* bs  = (const float*)d_in[8];
    const float* cw1 = (const float*)d_in[9];
    const float* cb1 = (const float*)d_in[10];
    const float* g1  = (const float*)d_in[11];
    const float* be1 = (const float*)d_in[12];
    const float* cw2 = (const float*)d_in[13];
    const float* cb2 = (const float*)d_in[14];
    const float* g2  = (const float*)d_in[15];
    const float* be2 = (const float*)d_in[16];
    const float* cw3 = (const float*)d_in[17];
    const float* cb3 = (const float*)d_in[18];
    const float* g3  = (const float*)d_in[19];
    const float* be3 = (const float*)d_in[20];

    // u16 region
    uint16_t* Qbf  = (uint16_t*)d_ws;                        // 4194304
    uint16_t* Csbf = Qbf + (size_t)4194304;                  // 2621440
    uint16_t* PS   = Csbf + (size_t)2621440;                 // 2621440
    uint16_t* WB   = PS + (size_t)2621440;                   // 131072
    uint16_t* Wk1  = WB + 131072;                            // 2048
    uint16_t* Wk2  = Wk1 + 2048;                             // 26624
    uint16_t* Wk3  = Wk2 + 26624;                            // 73728
    // float region
    float* fbase  = (float*)(Wk3 + 73728);
    float* mexpb  = fbase;                 // 10240
    float* inv    = mexpb + 10240;         // 10240
    float* sfbuf  = inv + 10240;           // 1048576
    float* cm     = sfbuf + 1048576;       // 16384
    float* h1     = cm + 16384;            // 65536
    float* h2     = h1 + 65536;            // 262144
    float* h3     = h2 + 262144;           // 524288
    float* gnpart = h3 + 524288;           // 256

    // fused prepack (WB + Wk1..3)
    prep_all<<<(233472 + 255) / 256, 256, 0, stream>>>(wq, wsm, cw1, cw2, cw3, WB, Wk1, Wk2, Wk3);

    // pipeline
    patch_sum<<<dim3(16, 4, 20), 256, 0, stream>>>(x0, x1, x2, x3, dox, PS, inv, mexpb);
    q_gemm<<<dim3(64, 4), 512, 0, stream>>>(x0, x1, x2, x3, WB, bq, Qbf);
    cent_gemm<<<dim3(80, 4), 256, 0, stream>>>(PS, WB, bs, inv, Csbf);
    attn_v7<<<dim3(16, NH, 16), 256, 0, stream>>>(Qbf, Csbf, mexpb, sfbuf);
    mean_heads3<<<64, 256, 0, stream>>>(sfbuf, cm);

    conv_mfma<4, 16, 5><<<dim3(64, 1), 256, 0, stream>>>(cm, Wk1, cb1, h1);
    gn_part<<<dim3(4, GN_NB), 256, 0, stream>>>(h1, 4, gnpart);
    gn_apply_relu<<<(16 * 1024) / 256, 256, 0, stream>>>(h1, gnpart, g1, be1, 4, h1);

    conv_mfma<16, 64, 5><<<dim3(64, 1), 256, 0, stream>>>(h1, Wk2, cb2, h2);
    gn_part<<<dim3(4, GN_NB), 256, 0, stream>>>(h2, 16, gnpart);
    gn_apply_relu<<<(64 * 1024) / 256, 256, 0, stream>>>(h2, gnpart, g2, be2, 16, h2);

    conv_mfma<64, 128, 3><<<dim3(64, 2), 256, 0, stream>>>(h2, Wk3, cb3, h3);
    gn_part<<<dim3(4, GN_NB), 256, 0, stream>>>(h3, 32, gnpart);
    gn_apply_relu<<<(128 * 1024) / 256, 256, 0, stream>>>(h3, gnpart, g3, be3, 32, (float*)d_out);
}